// Round 1
// baseline (362.357 us; speedup 1.0000x reference)
//
#include <hip/hip_runtime.h>
#include <hip/hip_bf16.h>
#include <math.h>

#define N_NODES  4096
#define HDIM     512
#define NUM_HEADS 8
#define HEAD_DIM 64
#define NUM_SETS 1365

// ---------------- segment bounds (batch_indices is sorted) ----------------
__global__ void seg_bounds_kernel(const int* __restrict__ batch, int n,
                                  int* __restrict__ seg_s, int* __restrict__ seg_e,
                                  int* __restrict__ set_s, int* __restrict__ set_e) {
    int i = blockIdx.x * blockDim.x + threadIdx.x;
    if (i >= n) return;
    int bi = batch[i];
    if (i == 0 || batch[i - 1] != bi) {          // segment head
        int e = i + 1;
        while (e < n && batch[e] == bi) ++e;
        for (int j = i; j < e; ++j) { seg_s[j] = i; seg_e[j] = e; }
        set_s[bi] = i; set_e[bi] = e;
    }
}

// ---------------- fp32 GEMM: C[4096,512] = A @ W + bias, epilogues ----------------
// EPI 0: +bias   EPI 1: relu(+bias)   EPI 2: beta*(+bias) + X (residual)
template<int EPI>
__global__ __launch_bounds__(256) void gemm512(
        const float* __restrict__ A, const float* __restrict__ W,
        const float* __restrict__ bias, const float* __restrict__ X,
        const float* __restrict__ betaP, float* __restrict__ C) {
    __shared__ float Ast[16][68];   // [k][row], padded: stride 68*4B = 17*16B (b128-aligned, conflict-free)
    __shared__ float Wst[16][68];   // [k][col]
    const int tid = threadIdx.x;
    const int tx = tid & 15, ty = tid >> 4;
    const int brow = blockIdx.x * 64, bcol = blockIdx.y * 64;
    // staging assignments
    const int lr = tid >> 2, lk = (tid & 3) * 4;   // A: row lr in [0,64), k-chunk lk
    const int wr = tid >> 4, wc = (tid & 15) * 4;  // W: k-row wr in [0,16), col chunk wc
    const float* Ap = A + (size_t)(brow + lr) * HDIM + lk;
    const float* Wp = W + (size_t)wr * HDIM + bcol + wc;

    float acc[4][4] = {};
    for (int k0 = 0; k0 < HDIM; k0 += 16) {
        float4 av = *(const float4*)(Ap + k0);
        float4 wv = *(const float4*)(Wp + (size_t)k0 * HDIM);
        Ast[lk + 0][lr] = av.x; Ast[lk + 1][lr] = av.y;
        Ast[lk + 2][lr] = av.z; Ast[lk + 3][lr] = av.w;
        *(float4*)&Wst[wr][wc] = wv;
        __syncthreads();
        #pragma unroll
        for (int kk = 0; kk < 16; ++kk) {
            float4 a4 = *(const float4*)&Ast[kk][ty * 4];
            float4 w4 = *(const float4*)&Wst[kk][tx * 4];
            float ar[4] = {a4.x, a4.y, a4.z, a4.w};
            float wr4[4] = {w4.x, w4.y, w4.z, w4.w};
            #pragma unroll
            for (int i = 0; i < 4; ++i)
                #pragma unroll
                for (int j = 0; j < 4; ++j)
                    acc[i][j] = fmaf(ar[i], wr4[j], acc[i][j]);
        }
        __syncthreads();
    }

    const float beta = (EPI == 2) ? betaP[0] : 0.f;
    #pragma unroll
    for (int i = 0; i < 4; ++i) {
        const int r = brow + ty * 4 + i;
        float out[4];
        #pragma unroll
        for (int j = 0; j < 4; ++j) {
            float v = acc[i][j] + bias[bcol + tx * 4 + j];
            if (EPI == 1) v = fmaxf(v, 0.f);
            out[j] = v;
        }
        if (EPI == 2) {
            const float4 xv = *(const float4*)&X[(size_t)r * HDIM + bcol + tx * 4];
            out[0] = beta * out[0] + xv.x; out[1] = beta * out[1] + xv.y;
            out[2] = beta * out[2] + xv.z; out[3] = beta * out[3] + xv.w;
        }
        float4 o4 = make_float4(out[0], out[1], out[2], out[3]);
        *(float4*)&C[(size_t)r * HDIM + bcol + tx * 4] = o4;
    }
}

// ---------------- masked segment attention, online softmax ----------------
// one wave per (node, head); lane = d in [0,64)
__global__ __launch_bounds__(256) void attn_kernel(
        const float* __restrict__ q, const float* __restrict__ k,
        const float* __restrict__ v,
        const int* __restrict__ seg_s, const int* __restrict__ seg_e,
        float* __restrict__ attn) {
    const int wid  = (blockIdx.x * blockDim.x + threadIdx.x) >> 6;
    const int lane = threadIdx.x & 63;
    const int node = wid >> 3;
    const int head = wid & 7;
    const int col  = head * HEAD_DIM + lane;

    const float qv = q[(size_t)node * HDIM + col];
    const int s = seg_s[node], e = seg_e[node];

    float M = -INFINITY, S = 0.f, o = 0.f;
    for (int m = s; m < e; ++m) {
        if (m == node) continue;
        float p = qv * k[(size_t)m * HDIM + col];
        #pragma unroll
        for (int off = 32; off; off >>= 1) p += __shfl_xor(p, off, 64);
        const float sc = p * 0.125f;                 // / sqrt(64)
        const float newM = fmaxf(M, sc);
        const float scale = __expf(M - newM);        // exp(-inf)=0 on first hit
        const float w = __expf(sc - newM);
        S = S * scale + w;
        o = o * scale + w * v[(size_t)m * HDIM + col];
        M = newM;
    }
    attn[(size_t)node * HDIM + col] = (S > 0.f) ? (o / S) : 0.f;
}

// ---------------- per-set mean of squared diff ----------------
__global__ __launch_bounds__(256) void seg_mse_kernel(
        const float* __restrict__ dyn, const float* __restrict__ stat,
        const int* __restrict__ set_s, const int* __restrict__ set_e,
        float* __restrict__ out) {
    const int s = blockIdx.x;          // 1365 sets
    const int d = threadIdx.x;         // cols d and d+256
    const int a = set_s[s], b = set_e[s];
    float acc0 = 0.f, acc1 = 0.f;
    for (int i = a; i < b; ++i) {
        const float d0 = dyn[(size_t)i * HDIM + d]       - stat[(size_t)i * HDIM + d];
        const float d1 = dyn[(size_t)i * HDIM + d + 256] - stat[(size_t)i * HDIM + d + 256];
        acc0 += d0 * d0; acc1 += d1 * d1;
    }
    const float inv = 1.f / fmaxf((float)(b - a), 1.f);  // empty set -> 0
    out[(size_t)s * HDIM + d]       = acc0 * inv;
    out[(size_t)s * HDIM + d + 256] = acc1 * inv;
}

extern "C" void kernel_launch(void* const* d_in, const int* in_sizes, int n_in,
                              void* d_out, int out_size, void* d_ws, size_t ws_size,
                              hipStream_t stream) {
    const float* emb   = (const float*)d_in[0];
    const int*   batch = (const int*)  d_in[1];
    const float* Ws_   = (const float*)d_in[2];
    const float* bs_   = (const float*)d_in[3];
    const float* Wq1 = (const float*)d_in[4];  const float* bq1 = (const float*)d_in[5];
    const float* Wk1 = (const float*)d_in[6];  const float* bk1 = (const float*)d_in[7];
    const float* Wv1 = (const float*)d_in[8];  const float* bv1 = (const float*)d_in[9];
    const float* Wo1 = (const float*)d_in[10]; const float* bo1 = (const float*)d_in[11];
    const float* beta1 = (const float*)d_in[12];
    const float* Wq2 = (const float*)d_in[13]; const float* bq2 = (const float*)d_in[14];
    const float* Wk2 = (const float*)d_in[15]; const float* bk2 = (const float*)d_in[16];
    const float* Wv2 = (const float*)d_in[17]; const float* bv2 = (const float*)d_in[18];
    const float* Wo2 = (const float*)d_in[19]; const float* bo2 = (const float*)d_in[20];
    const float* beta2 = (const float*)d_in[21];

    float* ws = (float*)d_ws;
    const size_t B = (size_t)N_NODES * HDIM;   // 2M floats per buffer
    float* stat = ws;
    float* dyn  = ws + 1 * B;
    float* qb   = ws + 2 * B;
    float* kb   = ws + 3 * B;
    float* vb   = ws + 4 * B;
    float* ab   = ws + 5 * B;
    int* seg_s = (int*)(ws + 6 * B);
    int* seg_e = seg_s + N_NODES;
    int* set_s = seg_e + N_NODES;
    int* set_e = set_s + NUM_SETS;
    // total ws use: 48 MiB + ~44 KiB

    hipMemsetAsync(set_s, 0, 2 * NUM_SETS * sizeof(int), stream);
    seg_bounds_kernel<<<(N_NODES + 255) / 256, 256, 0, stream>>>(
        batch, N_NODES, seg_s, seg_e, set_s, set_e);

    dim3 gg(64, 8), gb(256);
    // static branch
    gemm512<1><<<gg, gb, 0, stream>>>(emb, Ws_, bs_, nullptr, nullptr, stat);
    // layer 1
    gemm512<0><<<gg, gb, 0, stream>>>(emb, Wq1, bq1, nullptr, nullptr, qb);
    gemm512<0><<<gg, gb, 0, stream>>>(emb, Wk1, bk1, nullptr, nullptr, kb);
    gemm512<0><<<gg, gb, 0, stream>>>(emb, Wv1, bv1, nullptr, nullptr, vb);
    attn_kernel<<<N_NODES * NUM_HEADS / 4, 256, 0, stream>>>(qb, kb, vb, seg_s, seg_e, ab);
    gemm512<2><<<gg, gb, 0, stream>>>(ab, Wo1, bo1, emb, beta1, dyn);
    // layer 2
    gemm512<0><<<gg, gb, 0, stream>>>(dyn, Wq2, bq2, nullptr, nullptr, qb);
    gemm512<0><<<gg, gb, 0, stream>>>(dyn, Wk2, bk2, nullptr, nullptr, kb);
    gemm512<0><<<gg, gb, 0, stream>>>(dyn, Wv2, bv2, nullptr, nullptr, vb);
    attn_kernel<<<N_NODES * NUM_HEADS / 4, 256, 0, stream>>>(qb, kb, vb, seg_s, seg_e, ab);
    float* dyn2 = qb;  // reuse q buffer (free after attn)
    gemm512<2><<<gg, gb, 0, stream>>>(ab, Wo2, bo2, dyn, beta2, dyn2);
    // reduction
    seg_mse_kernel<<<NUM_SETS, 256, 0, stream>>>(dyn2, stat, set_s, set_e, (float*)d_out);
}

// Round 2
// 125.961 us; speedup vs baseline: 2.8767x; 2.8767x over previous
//
#include <hip/hip_runtime.h>
#include <hip/hip_bf16.h>
#include <math.h>
#include <stdint.h>

#define N_NODES   4096
#define HDIM      512
#define NUM_HEADS 8
#define HEAD_DIM  64
#define NUM_SETS  1365
#define KDIM      512

typedef __attribute__((ext_vector_type(8))) short bf16x8;
typedef __attribute__((ext_vector_type(4))) float f32x4;

__device__ inline unsigned short f2bfu(float x) {
    __hip_bfloat16 h = __float2bfloat16(x);
    return __builtin_bit_cast(unsigned short, h);
}

__device__ inline void gload_lds16(const void* g, void* l) {
    __builtin_amdgcn_global_load_lds(
        (const __attribute__((address_space(1))) unsigned int*)g,
        (__attribute__((address_space(3))) unsigned int*)l,
        16, 0, 0);
}

// ---------------- segment bounds (batch_indices is sorted) ----------------
__global__ void seg_bounds_kernel(const int* __restrict__ batch, int n,
                                  int* __restrict__ seg_s, int* __restrict__ seg_e,
                                  int* __restrict__ set_s, int* __restrict__ set_e) {
    int i = blockIdx.x * blockDim.x + threadIdx.x;
    if (i >= n) return;
    int bi = batch[i];
    if (i == 0 || batch[i - 1] != bi) {          // segment head
        int e = i + 1;
        while (e < n && batch[e] == bi) ++e;
        for (int j = i; j < e; ++j) { seg_s[j] = i; seg_e[j] = e; }
        set_s[bi] = i; set_e[bi] = e;
    }
}

// ---------------- fp32 -> bf16 elementwise (vectorized) ----------------
__global__ __launch_bounds__(256) void f2bf4_kernel(const float* __restrict__ in,
                                                    __hip_bfloat16* __restrict__ out, int n4) {
    int i = blockIdx.x * 256 + threadIdx.x;
    if (i >= n4) return;
    float4 v = ((const float4*)in)[i];
    uint2 p;
    p.x = (unsigned)f2bfu(v.x) | ((unsigned)f2bfu(v.y) << 16);
    p.y = (unsigned)f2bfu(v.z) | ((unsigned)f2bfu(v.w) << 16);
    ((uint2*)out)[i] = p;
}

// ---------------- weight transpose + convert: Wt[n][k] = bf16(W[k][n]) ----------------
__global__ __launch_bounds__(256) void wconv_kernel(
        const float* W0, const float* W1, const float* W2, const float* W3,
        const float* W4, const float* W5, const float* W6, const float* W7,
        const float* W8, __hip_bfloat16* __restrict__ wt) {
    __shared__ float t[32][33];
    const int z = blockIdx.z;
    const float* W = z==0?W0:z==1?W1:z==2?W2:z==3?W3:z==4?W4:z==5?W5:z==6?W6:z==7?W7:W8;
    __hip_bfloat16* Wt = wt + (size_t)z * (512 * 512);
    const int bn = blockIdx.x * 32;   // n tile
    const int bk = blockIdx.y * 32;   // k tile
    const int tx = threadIdx.x & 31, ty = threadIdx.x >> 5;   // 32 x 8
    #pragma unroll
    for (int i = 0; i < 4; ++i)
        t[ty + i * 8][tx] = W[(size_t)(bk + ty + i * 8) * 512 + bn + tx];
    __syncthreads();
    #pragma unroll
    for (int i = 0; i < 4; ++i)
        Wt[(size_t)(bn + ty + i * 8) * 512 + bk + tx] = __float2bfloat16(t[tx][ty + i * 8]);
}

// ---------------- bf16 MFMA GEMM, 128x64 tile, BK=32, m97 structure ----------------
// MODE 0: layer-1 fused, grid.y=32: wsel=y>>3 (0:static->relu->outF f32; 1..3: qkv->outB bf16)
// MODE 1: layer-2 fused, grid.y=24: wsel=y>>3 (0..2: qkv->outB bf16)
// MODE 2: O-proj,        grid.y=8:  outF = beta*(acc+bias)+X (f32), outB = bf16(outF) if non-null
template<int MODE>
__global__ __launch_bounds__(256) void gemm_mf(
        const __hip_bfloat16* __restrict__ A,
        const __hip_bfloat16* __restrict__ Wt0, const __hip_bfloat16* __restrict__ Wt1,
        const __hip_bfloat16* __restrict__ Wt2, const __hip_bfloat16* __restrict__ Wt3,
        const float* __restrict__ bias0, const float* __restrict__ bias1,
        const float* __restrict__ bias2, const float* __restrict__ bias3,
        float* __restrict__ outF, __hip_bfloat16* __restrict__ outB,
        const float* __restrict__ X, const float* __restrict__ betaP) {
    __shared__ alignas(16) short Al[128][32];
    __shared__ alignas(16) short Bl[64][32];

    const int tid = threadIdx.x;
    const int wid = tid >> 6, lane = tid & 63;
    const int brow = blockIdx.x * 128;
    int wsel, bcolL;
    if (MODE == 2) { wsel = 0; bcolL = blockIdx.y * 64; }
    else           { wsel = blockIdx.y >> 3; bcolL = (blockIdx.y & 7) * 64; }
    const __hip_bfloat16* Wt = (wsel == 0) ? Wt0 : (wsel == 1) ? Wt1 : (wsel == 2) ? Wt2 : Wt3;
    const float* bias        = (wsel == 0) ? bias0 : (wsel == 1) ? bias1 : (wsel == 2) ? bias2 : bias3;

    // staging: wave w covers A rows [w*32, w*32+32) (2 issues) and B rows [w*16, w*16+16)
    const __hip_bfloat16* aSrc = A  + (size_t)(brow  + wid * 32 + (lane >> 2)) * KDIM + (lane & 3) * 8;
    const __hip_bfloat16* bSrc = Wt + (size_t)(bcolL + wid * 16 + (lane >> 2)) * KDIM + (lane & 3) * 8;
    short* aDst0 = &Al[wid * 32][0];
    short* aDst1 = &Al[wid * 32 + 16][0];
    short* bDst  = &Bl[wid * 16][0];

    const int fr = lane & 15, fq = lane >> 4;
    const int wm = (wid >> 1) * 64, wn = (wid & 1) * 32;

    f32x4 acc[4][2] = {};
    for (int k0 = 0; k0 < KDIM; k0 += 32) {
        gload_lds16(aSrc + k0, aDst0);
        gload_lds16(aSrc + k0 + (size_t)16 * KDIM, aDst1);
        gload_lds16(bSrc + k0, bDst);
        __syncthreads();
        bf16x8 af[4], bfr[2];
        #pragma unroll
        for (int mi = 0; mi < 4; ++mi)
            af[mi] = *(const bf16x8*)&Al[wm + mi * 16 + fr][fq * 8];
        #pragma unroll
        for (int ni = 0; ni < 2; ++ni)
            bfr[ni] = *(const bf16x8*)&Bl[wn + ni * 16 + fr][fq * 8];
        #pragma unroll
        for (int mi = 0; mi < 4; ++mi)
            #pragma unroll
            for (int ni = 0; ni < 2; ++ni)
                acc[mi][ni] = __builtin_amdgcn_mfma_f32_16x16x32_bf16(af[mi], bfr[ni], acc[mi][ni], 0, 0, 0);
        __syncthreads();
    }

    float bv[2];
    #pragma unroll
    for (int ni = 0; ni < 2; ++ni) bv[ni] = bias[bcolL + wn + ni * 16 + fr];
    const float beta = (MODE == 2) ? betaP[0] : 0.f;
    const bool wb = (outB != nullptr);

    #pragma unroll
    for (int mi = 0; mi < 4; ++mi) {
        #pragma unroll
        for (int ni = 0; ni < 2; ++ni) {
            const int c = bcolL + wn + ni * 16 + fr;
            #pragma unroll
            for (int r = 0; r < 4; ++r) {
                const int row = brow + wm + mi * 16 + fq * 4 + r;
                float v = acc[mi][ni][r] + bv[ni];
                if (MODE == 0) {
                    if (wsel == 0) outF[(size_t)row * 512 + c] = fmaxf(v, 0.f);
                    else           outB[(size_t)row * 1536 + (wsel - 1) * 512 + c] = __float2bfloat16(v);
                } else if (MODE == 1) {
                    outB[(size_t)row * 1536 + wsel * 512 + c] = __float2bfloat16(v);
                } else {
                    v = beta * v + X[(size_t)row * 512 + c];
                    outF[(size_t)row * 512 + c] = v;
                    if (wb) outB[(size_t)row * 512 + c] = __float2bfloat16(v);
                }
            }
        }
    }
}

// ---------------- masked segment attention, online softmax, bf16 I/O ----------------
// one wave per (node, head); lane = d in [0,64); qkv layout [node][3*512] = q|k|v
__global__ __launch_bounds__(256) void attn_kernel(
        const __hip_bfloat16* __restrict__ qkv,
        const int* __restrict__ seg_s, const int* __restrict__ seg_e,
        __hip_bfloat16* __restrict__ ab) {
    const int wid  = (blockIdx.x * blockDim.x + threadIdx.x) >> 6;
    const int lane = threadIdx.x & 63;
    const int node = wid >> 3;
    const int head = wid & 7;
    const int col  = head * HEAD_DIM + lane;

    const float qv = __bfloat162float(qkv[(size_t)node * 1536 + col]);
    const int s = seg_s[node], e = seg_e[node];

    float M = -INFINITY, S = 0.f, o = 0.f;
    for (int m = s; m < e; ++m) {
        if (m == node) continue;
        float p = qv * __bfloat162float(qkv[(size_t)m * 1536 + 512 + col]);
        #pragma unroll
        for (int off = 32; off; off >>= 1) p += __shfl_xor(p, off, 64);
        const float sc = p * 0.125f;                 // / sqrt(64)
        const float newM = fmaxf(M, sc);
        const float scale = __expf(M - newM);        // exp(-inf)=0 on first hit
        const float w = __expf(sc - newM);
        S = S * scale + w;
        o = o * scale + w * __bfloat162float(qkv[(size_t)m * 1536 + 1024 + col]);
        M = newM;
    }
    ab[(size_t)node * 512 + col] = __float2bfloat16((S > 0.f) ? (o / S) : 0.f);
}

// ---------------- per-set mean of squared diff ----------------
__global__ __launch_bounds__(256) void seg_mse_kernel(
        const float* __restrict__ dyn, const float* __restrict__ stat,
        const int* __restrict__ set_s, const int* __restrict__ set_e,
        float* __restrict__ out) {
    const int s = blockIdx.x;
    const int d = threadIdx.x;
    const int a = set_s[s], b = set_e[s];
    float acc0 = 0.f, acc1 = 0.f;
    for (int i = a; i < b; ++i) {
        const float d0 = dyn[(size_t)i * 512 + d]       - stat[(size_t)i * 512 + d];
        const float d1 = dyn[(size_t)i * 512 + d + 256] - stat[(size_t)i * 512 + d + 256];
        acc0 += d0 * d0; acc1 += d1 * d1;
    }
    const float inv = 1.f / fmaxf((float)(b - a), 1.f);
    out[(size_t)s * 512 + d]       = acc0 * inv;
    out[(size_t)s * 512 + d + 256] = acc1 * inv;
}

extern "C" void kernel_launch(void* const* d_in, const int* in_sizes, int n_in,
                              void* d_out, int out_size, void* d_ws, size_t ws_size,
                              hipStream_t stream) {
    const float* emb   = (const float*)d_in[0];
    const int*   batch = (const int*)  d_in[1];
    const float* Ws_   = (const float*)d_in[2];
    const float* bs_   = (const float*)d_in[3];
    const float* Wq1 = (const float*)d_in[4];  const float* bq1 = (const float*)d_in[5];
    const float* Wk1 = (const float*)d_in[6];  const float* bk1 = (const float*)d_in[7];
    const float* Wv1 = (const float*)d_in[8];  const float* bv1 = (const float*)d_in[9];
    const float* Wo1 = (const float*)d_in[10]; const float* bo1 = (const float*)d_in[11];
    const float* beta1 = (const float*)d_in[12];
    const float* Wq2 = (const float*)d_in[13]; const float* bq2 = (const float*)d_in[14];
    const float* Wk2 = (const float*)d_in[15]; const float* bk2 = (const float*)d_in[16];
    const float* Wv2 = (const float*)d_in[17]; const float* bv2 = (const float*)d_in[18];
    const float* Wo2 = (const float*)d_in[19]; const float* bo2 = (const float*)d_in[20];
    const float* beta2 = (const float*)d_in[21];

    char* w = (char*)d_ws;
    const size_t MB = 1024 * 1024;
    float* stat            = (float*)(w + 0 * MB);            // 8 MiB
    float* dyn             = (float*)(w + 8 * MB);            // 8 MiB
    __hip_bfloat16* qkv    = (__hip_bfloat16*)(w + 16 * MB);  // 12 MiB
    float* dyn2            = (float*)(w + 16 * MB);           // overlaps qkv (qkv dead by then)
    __hip_bfloat16* embb   = (__hip_bfloat16*)(w + 28 * MB);  // 4 MiB
    __hip_bfloat16* ab     = (__hip_bfloat16*)(w + 32 * MB);  // 4 MiB
    __hip_bfloat16* dynb   = (__hip_bfloat16*)(w + 36 * MB);  // 4 MiB
    __hip_bfloat16* wt     = (__hip_bfloat16*)(w + 40 * MB);  // 4.5 MiB (9 x 512x512)
    int* seg_s = (int*)(w + 45 * MB);
    int* seg_e = seg_s + N_NODES;
    int* set_s = seg_e + N_NODES;
    int* set_e = set_s + NUM_SETS;

    const size_t WSZ = 512 * 512;
    __hip_bfloat16* wtS  = wt + 0 * WSZ;
    __hip_bfloat16* wtQ1 = wt + 1 * WSZ;
    __hip_bfloat16* wtK1 = wt + 2 * WSZ;
    __hip_bfloat16* wtV1 = wt + 3 * WSZ;
    __hip_bfloat16* wtO1 = wt + 4 * WSZ;
    __hip_bfloat16* wtQ2 = wt + 5 * WSZ;
    __hip_bfloat16* wtK2 = wt + 6 * WSZ;
    __hip_bfloat16* wtV2 = wt + 7 * WSZ;
    __hip_bfloat16* wtO2 = wt + 8 * WSZ;

    hipMemsetAsync(set_s, 0, 2 * NUM_SETS * sizeof(int), stream);
    seg_bounds_kernel<<<(N_NODES + 255) / 256, 256, 0, stream>>>(
        batch, N_NODES, seg_s, seg_e, set_s, set_e);

    f2bf4_kernel<<<(N_NODES * HDIM / 4 + 255) / 256, 256, 0, stream>>>(emb, embb, N_NODES * HDIM / 4);
    wconv_kernel<<<dim3(16, 16, 9), 256, 0, stream>>>(
        Ws_, Wq1, Wk1, Wv1, Wo1, Wq2, Wk2, Wv2, Wo2, wt);

    // layer 1: fused static + QKV  (N = 2048)
    gemm_mf<0><<<dim3(32, 32), 256, 0, stream>>>(
        embb, wtS, wtQ1, wtK1, wtV1, bs_, bq1, bk1, bv1, stat, qkv, nullptr, nullptr);
    attn_kernel<<<N_NODES * NUM_HEADS / 4, 256, 0, stream>>>(qkv, seg_s, seg_e, ab);
    gemm_mf<2><<<dim3(32, 8), 256, 0, stream>>>(
        ab, wtO1, wtO1, wtO1, wtO1, bo1, bo1, bo1, bo1, dyn, dynb, emb, beta1);

    // layer 2: fused QKV (N = 1536)
    gemm_mf<1><<<dim3(32, 24), 256, 0, stream>>>(
        dynb, wtQ2, wtK2, wtV2, wtV2, bq2, bk2, bv2, bv2, nullptr, qkv, nullptr, nullptr);
    attn_kernel<<<N_NODES * NUM_HEADS / 4, 256, 0, stream>>>(qkv, seg_s, seg_e, ab);
    gemm_mf<2><<<dim3(32, 8), 256, 0, stream>>>(
        ab, wtO2, wtO2, wtO2, wtO2, bo2, bo2, bo2, bo2, dyn2, nullptr, dyn, beta2);

    seg_mse_kernel<<<NUM_SETS, 256, 0, stream>>>(dyn2, stat, set_s, set_e, (float*)d_out);
}

// Round 3
// 119.092 us; speedup vs baseline: 3.0427x; 1.0577x over previous
//
#include <hip/hip_runtime.h>
#include <hip/hip_bf16.h>
#include <math.h>
#include <stdint.h>

#define N_NODES   4096
#define HDIM      512
#define NUM_HEADS 8
#define HEAD_DIM  64
#define NUM_SETS  1365
#define KDIM      512

typedef __attribute__((ext_vector_type(8))) short bf16x8;
typedef __attribute__((ext_vector_type(4))) float f32x4;

__device__ inline unsigned short f2bfu(float x) {
    __hip_bfloat16 h = __float2bfloat16(x);
    return __builtin_bit_cast(unsigned short, h);
}

__device__ inline void gload_lds16(const void* g, void* l) {
    __builtin_amdgcn_global_load_lds(
        (const __attribute__((address_space(1))) unsigned int*)g,
        (__attribute__((address_space(3))) unsigned int*)l,
        16, 0, 0);
}

// ---------------- fused prelude: wconv (blocks 0..2303) | f2bf4 (..4351) | seg_bounds (..4367)
__global__ __launch_bounds__(256) void prep_kernel(
        const float* W0, const float* W1, const float* W2, const float* W3,
        const float* W4, const float* W5, const float* W6, const float* W7,
        const float* W8, __hip_bfloat16* __restrict__ wt,
        const float* __restrict__ emb, __hip_bfloat16* __restrict__ embb,
        const int* __restrict__ batch,
        int* __restrict__ seg_s, int* __restrict__ seg_e) {
    const int bx = blockIdx.x;
    if (bx < 2304) {
        // weight transpose+convert: Wt[n][k] = bf16(W[k][n]), 32x32 tiles
        __shared__ float t[32][33];
        const int z = bx >> 8;
        const int tb = bx & 255;
        const float* W = z==0?W0:z==1?W1:z==2?W2:z==3?W3:z==4?W4:z==5?W5:z==6?W6:z==7?W7:W8;
        __hip_bfloat16* Wt = wt + (size_t)z * (512 * 512);
        const int bn = (tb & 15) * 32, bk = (tb >> 4) * 32;
        const int tx = threadIdx.x & 31, ty = threadIdx.x >> 5;
        #pragma unroll
        for (int i = 0; i < 4; ++i)
            t[ty + i * 8][tx] = W[(size_t)(bk + ty + i * 8) * 512 + bn + tx];
        __syncthreads();
        #pragma unroll
        for (int i = 0; i < 4; ++i)
            Wt[(size_t)(bn + ty + i * 8) * 512 + bk + tx] = __float2bfloat16(t[tx][ty + i * 8]);
    } else if (bx < 4352) {
        // emb fp32 -> bf16, 4 elems/thread
        const int i = (bx - 2304) * 256 + threadIdx.x;   // < 524288
        float4 v = ((const float4*)emb)[i];
        uint2 p;
        p.x = (unsigned)f2bfu(v.x) | ((unsigned)f2bfu(v.y) << 16);
        p.y = (unsigned)f2bfu(v.z) | ((unsigned)f2bfu(v.w) << 16);
        ((uint2*)embb)[i] = p;
    } else {
        // segment bounds (batch sorted)
        const int i = (bx - 4352) * 256 + threadIdx.x;   // < 4096
        const int bi = batch[i];
        if (i == 0 || batch[i - 1] != bi) {
            int e = i + 1;
            while (e < N_NODES && batch[e] == bi) ++e;
            for (int j = i; j < e; ++j) { seg_s[j] = i; seg_e[j] = e; }
        }
    }
}

// ---------------- bf16 MFMA GEMM, 128x128 tile, BK=32 (m97 structure) ----------------
// MODE 0: grid.y=16, wsel=y>>2 (0: static->relu->outF f32; 1..3: qkv->outB bf16 interleaved)
// MODE 1: grid.y=12, wsel=y>>2 (0..2: qkv->outB bf16 interleaved)
template<int MODE>
__global__ __launch_bounds__(256) void gemm128(
        const __hip_bfloat16* __restrict__ A,
        const __hip_bfloat16* __restrict__ Wt0, const __hip_bfloat16* __restrict__ Wt1,
        const __hip_bfloat16* __restrict__ Wt2, const __hip_bfloat16* __restrict__ Wt3,
        const float* __restrict__ bias0, const float* __restrict__ bias1,
        const float* __restrict__ bias2, const float* __restrict__ bias3,
        float* __restrict__ outF, __hip_bfloat16* __restrict__ outB) {
    __shared__ alignas(16) short Al[128][32];
    __shared__ alignas(16) short Bl[128][32];

    const int tid = threadIdx.x;
    const int wid = tid >> 6, lane = tid & 63;
    const int brow = blockIdx.x * 128;
    const int wsel = blockIdx.y >> 2;
    const int bcol = (blockIdx.y & 3) * 128;
    const __hip_bfloat16* Wt = (wsel == 0) ? Wt0 : (wsel == 1) ? Wt1 : (wsel == 2) ? Wt2 : Wt3;
    const float* bias        = (wsel == 0) ? bias0 : (wsel == 1) ? bias1 : (wsel == 2) ? bias2 : bias3;

    // staging: wave w covers A rows [w*32, w*32+32) and B rows [w*32, w*32+32), 2 issues each
    const __hip_bfloat16* aSrc = A  + (size_t)(brow + wid * 32 + (lane >> 2)) * KDIM + (lane & 3) * 8;
    const __hip_bfloat16* bSrc = Wt + (size_t)(bcol + wid * 32 + (lane >> 2)) * KDIM + (lane & 3) * 8;
    short* aD0 = &Al[wid * 32][0];      short* aD1 = &Al[wid * 32 + 16][0];
    short* bD0 = &Bl[wid * 32][0];      short* bD1 = &Bl[wid * 32 + 16][0];

    const int fr = lane & 15, fq = lane >> 4;
    const int wm = (wid >> 1) * 64, wn = (wid & 1) * 64;

    f32x4 acc[4][4] = {};
    for (int k0 = 0; k0 < KDIM; k0 += 32) {
        gload_lds16(aSrc + k0, aD0);
        gload_lds16(aSrc + k0 + (size_t)16 * KDIM, aD1);
        gload_lds16(bSrc + k0, bD0);
        gload_lds16(bSrc + k0 + (size_t)16 * KDIM, bD1);
        __syncthreads();
        bf16x8 af[4], bfv[4];
        #pragma unroll
        for (int mi = 0; mi < 4; ++mi)
            af[mi] = *(const bf16x8*)&Al[wm + mi * 16 + fr][fq * 8];
        #pragma unroll
        for (int ni = 0; ni < 4; ++ni)
            bfv[ni] = *(const bf16x8*)&Bl[wn + ni * 16 + fr][fq * 8];
        #pragma unroll
        for (int mi = 0; mi < 4; ++mi)
            #pragma unroll
            for (int ni = 0; ni < 4; ++ni)
                acc[mi][ni] = __builtin_amdgcn_mfma_f32_16x16x32_bf16(af[mi], bfv[ni], acc[mi][ni], 0, 0, 0);
        __syncthreads();
    }

    float bv[4];
    #pragma unroll
    for (int ni = 0; ni < 4; ++ni) bv[ni] = bias[bcol + wn + ni * 16 + fr];

    #pragma unroll
    for (int mi = 0; mi < 4; ++mi) {
        #pragma unroll
        for (int ni = 0; ni < 4; ++ni) {
            const int c = bcol + wn + ni * 16 + fr;
            #pragma unroll
            for (int r = 0; r < 4; ++r) {
                const int row = brow + wm + mi * 16 + fq * 4 + r;
                const float v = acc[mi][ni][r] + bv[ni];
                if (MODE == 0) {
                    if (wsel == 0) outF[(size_t)row * 512 + c] = fmaxf(v, 0.f);
                    else           outB[(size_t)row * 1536 + (wsel - 1) * 512 + c] = __float2bfloat16(v);
                } else {
                    outB[(size_t)row * 1536 + wsel * 512 + c] = __float2bfloat16(v);
                }
            }
        }
    }
}

// ---------------- O-projection GEMM, 128x64 tile: outF = beta*(A@Wt+b)+X, outB = bf16(outF)
__global__ __launch_bounds__(256) void gemm_oproj(
        const __hip_bfloat16* __restrict__ A, const __hip_bfloat16* __restrict__ Wt,
        const float* __restrict__ bias,
        float* __restrict__ outF, __hip_bfloat16* __restrict__ outB,
        const float* __restrict__ X, const float* __restrict__ betaP) {
    __shared__ alignas(16) short Al[128][32];
    __shared__ alignas(16) short Bl[64][32];

    const int tid = threadIdx.x;
    const int wid = tid >> 6, lane = tid & 63;
    const int brow = blockIdx.x * 128;
    const int bcol = blockIdx.y * 64;

    const __hip_bfloat16* aSrc = A  + (size_t)(brow + wid * 32 + (lane >> 2)) * KDIM + (lane & 3) * 8;
    const __hip_bfloat16* bSrc = Wt + (size_t)(bcol + wid * 16 + (lane >> 2)) * KDIM + (lane & 3) * 8;
    short* aD0 = &Al[wid * 32][0];
    short* aD1 = &Al[wid * 32 + 16][0];
    short* bD  = &Bl[wid * 16][0];

    const int fr = lane & 15, fq = lane >> 4;
    const int wm = (wid >> 1) * 64, wn = (wid & 1) * 32;

    f32x4 acc[4][2] = {};
    for (int k0 = 0; k0 < KDIM; k0 += 32) {
        gload_lds16(aSrc + k0, aD0);
        gload_lds16(aSrc + k0 + (size_t)16 * KDIM, aD1);
        gload_lds16(bSrc + k0, bD);
        __syncthreads();
        bf16x8 af[4], bfv[2];
        #pragma unroll
        for (int mi = 0; mi < 4; ++mi)
            af[mi] = *(const bf16x8*)&Al[wm + mi * 16 + fr][fq * 8];
        #pragma unroll
        for (int ni = 0; ni < 2; ++ni)
            bfv[ni] = *(const bf16x8*)&Bl[wn + ni * 16 + fr][fq * 8];
        #pragma unroll
        for (int mi = 0; mi < 4; ++mi)
            #pragma unroll
            for (int ni = 0; ni < 2; ++ni)
                acc[mi][ni] = __builtin_amdgcn_mfma_f32_16x16x32_bf16(af[mi], bfv[ni], acc[mi][ni], 0, 0, 0);
        __syncthreads();
    }

    float bv[2];
    #pragma unroll
    for (int ni = 0; ni < 2; ++ni) bv[ni] = bias[bcol + wn + ni * 16 + fr];
    const float beta = betaP[0];
    const bool wb = (outB != nullptr);

    #pragma unroll
    for (int mi = 0; mi < 4; ++mi) {
        #pragma unroll
        for (int ni = 0; ni < 2; ++ni) {
            const int c = bcol + wn + ni * 16 + fr;
            #pragma unroll
            for (int r = 0; r < 4; ++r) {
                const int row = brow + wm + mi * 16 + fq * 4 + r;
                float v = beta * (acc[mi][ni][r] + bv[ni]) + X[(size_t)row * 512 + c];
                outF[(size_t)row * 512 + c] = v;
                if (wb) outB[(size_t)row * 512 + c] = __float2bfloat16(v);
            }
        }
    }
}

// ---------------- masked segment attention, online softmax, bf16 I/O ----------------
__global__ __launch_bounds__(256) void attn_kernel(
        const __hip_bfloat16* __restrict__ qkv,
        const int* __restrict__ seg_s, const int* __restrict__ seg_e,
        __hip_bfloat16* __restrict__ ab) {
    const int wid  = (blockIdx.x * blockDim.x + threadIdx.x) >> 6;
    const int lane = threadIdx.x & 63;
    const int node = wid >> 3;
    const int head = wid & 7;
    const int col  = head * HEAD_DIM + lane;

    const float qv = __bfloat162float(qkv[(size_t)node * 1536 + col]);
    const int s = seg_s[node], e = seg_e[node];

    float M = -INFINITY, S = 0.f, o = 0.f;
    for (int m = s; m < e; ++m) {
        if (m == node) continue;
        float p = qv * __bfloat162float(qkv[(size_t)m * 1536 + 512 + col]);
        #pragma unroll
        for (int off = 32; off; off >>= 1) p += __shfl_xor(p, off, 64);
        const float sc = p * 0.125f;
        const float newM = fmaxf(M, sc);
        const float scale = __expf(M - newM);
        const float w = __expf(sc - newM);
        S = S * scale + w;
        o = o * scale + w * __bfloat162float(qkv[(size_t)m * 1536 + 1024 + col]);
        M = newM;
    }
    ab[(size_t)node * 512 + col] = __float2bfloat16((S > 0.f) ? (o / S) : 0.f);
}

// ---------------- per-set mean of squared diff (binary-search set bounds) ----------------
__global__ __launch_bounds__(256) void seg_mse_kernel(
        const float* __restrict__ dyn, const float* __restrict__ stat,
        const int* __restrict__ batch, float* __restrict__ out) {
    const int s = blockIdx.x;
    const int d = threadIdx.x;
    int lo = 0, hi = N_NODES;
    while (lo < hi) { int m = (lo + hi) >> 1; if (batch[m] < s) lo = m + 1; else hi = m; }
    const int a = lo;
    hi = N_NODES;
    while (lo < hi) { int m = (lo + hi) >> 1; if (batch[m] <= s) lo = m + 1; else hi = m; }
    const int b = lo;

    float acc0 = 0.f, acc1 = 0.f;
    for (int i = a; i < b; ++i) {
        const float d0 = dyn[(size_t)i * 512 + d]       - stat[(size_t)i * 512 + d];
        const float d1 = dyn[(size_t)i * 512 + d + 256] - stat[(size_t)i * 512 + d + 256];
        acc0 += d0 * d0; acc1 += d1 * d1;
    }
    const float inv = 1.f / fmaxf((float)(b - a), 1.f);
    out[(size_t)s * 512 + d]       = acc0 * inv;
    out[(size_t)s * 512 + d + 256] = acc1 * inv;
}

extern "C" void kernel_launch(void* const* d_in, const int* in_sizes, int n_in,
                              void* d_out, int out_size, void* d_ws, size_t ws_size,
                              hipStream_t stream) {
    const float* emb   = (const float*)d_in[0];
    const int*   batch = (const int*)  d_in[1];
    const float* Ws_   = (const float*)d_in[2];
    const float* bs_   = (const float*)d_in[3];
    const float* Wq1 = (const float*)d_in[4];  const float* bq1 = (const float*)d_in[5];
    const float* Wk1 = (const float*)d_in[6];  const float* bk1 = (const float*)d_in[7];
    const float* Wv1 = (const float*)d_in[8];  const float* bv1 = (const float*)d_in[9];
    const float* Wo1 = (const float*)d_in[10]; const float* bo1 = (const float*)d_in[11];
    const float* beta1 = (const float*)d_in[12];
    const float* Wq2 = (const float*)d_in[13]; const float* bq2 = (const float*)d_in[14];
    const float* Wk2 = (const float*)d_in[15]; const float* bk2 = (const float*)d_in[16];
    const float* Wv2 = (const float*)d_in[17]; const float* bv2 = (const float*)d_in[18];
    const float* Wo2 = (const float*)d_in[19]; const float* bo2 = (const float*)d_in[20];
    const float* beta2 = (const float*)d_in[21];

    char* w = (char*)d_ws;
    const size_t MB = 1024 * 1024;
    float* stat            = (float*)(w + 0 * MB);            // 8 MiB
    float* dyn             = (float*)(w + 8 * MB);            // 8 MiB
    __hip_bfloat16* qkv    = (__hip_bfloat16*)(w + 16 * MB);  // 12 MiB
    float* dyn2            = (float*)(w + 16 * MB);           // overlaps qkv (qkv dead by then)
    __hip_bfloat16* embb   = (__hip_bfloat16*)(w + 28 * MB);  // 4 MiB
    __hip_bfloat16* ab     = (__hip_bfloat16*)(w + 32 * MB);  // 4 MiB
    __hip_bfloat16* dynb   = (__hip_bfloat16*)(w + 36 * MB);  // 4 MiB
    __hip_bfloat16* wt     = (__hip_bfloat16*)(w + 40 * MB);  // 4.5 MiB (9 x 512x512)
    int* seg_s = (int*)(w + 45 * MB);
    int* seg_e = seg_s + N_NODES;

    const size_t WSZ = 512 * 512;
    __hip_bfloat16* wtS  = wt + 0 * WSZ;
    __hip_bfloat16* wtQ1 = wt + 1 * WSZ;
    __hip_bfloat16* wtK1 = wt + 2 * WSZ;
    __hip_bfloat16* wtV1 = wt + 3 * WSZ;
    __hip_bfloat16* wtO1 = wt + 4 * WSZ;
    __hip_bfloat16* wtQ2 = wt + 5 * WSZ;
    __hip_bfloat16* wtK2 = wt + 6 * WSZ;
    __hip_bfloat16* wtV2 = wt + 7 * WSZ;
    __hip_bfloat16* wtO2 = wt + 8 * WSZ;

    // prelude: wconv(9 weights) + emb->bf16 + segment bounds, one launch
    prep_kernel<<<4368, 256, 0, stream>>>(
        Ws_, Wq1, Wk1, Wv1, Wo1, Wq2, Wk2, Wv2, Wo2, wt,
        emb, embb, batch, seg_s, seg_e);

    // layer 1: fused static + QKV  (effective N = 2048)
    gemm128<0><<<dim3(32, 16), 256, 0, stream>>>(
        embb, wtS, wtQ1, wtK1, wtV1, bs_, bq1, bk1, bv1, stat, qkv);
    attn_kernel<<<N_NODES * NUM_HEADS / 4, 256, 0, stream>>>(qkv, seg_s, seg_e, ab);
    gemm_oproj<<<dim3(32, 8), 256, 0, stream>>>(ab, wtO1, bo1, dyn, dynb, emb, beta1);

    // layer 2: fused QKV (effective N = 1536)
    gemm128<1><<<dim3(32, 12), 256, 0, stream>>>(
        dynb, wtQ2, wtK2, wtV2, wtV2, bq2, bk2, bv2, bv2, nullptr, qkv);
    attn_kernel<<<N_NODES * NUM_HEADS / 4, 256, 0, stream>>>(qkv, seg_s, seg_e, ab);
    gemm_oproj<<<dim3(32, 8), 256, 0, stream>>>(ab, wtO2, bo2, dyn2, nullptr, dyn, beta2);

    seg_mse_kernel<<<NUM_SETS, 256, 0, stream>>>(dyn2, stat, batch, (float*)d_out);
}